// Round 12
// baseline (141.933 us; speedup 1.0000x reference)
//
#include <hip/hip_runtime.h>

// Problem constants
#define B_  32
#define L_  2048
#define D_  256
#define T_  64
#define KW  3

typedef float f32x4 __attribute__((ext_vector_type(4)));
typedef short s16x8 __attribute__((ext_vector_type(8)));
typedef short s16x4 __attribute__((ext_vector_type(4)));

__device__ __forceinline__ short f2bf(float f) {
    unsigned u = __builtin_bit_cast(unsigned, f);
    u += 0x7FFFu + ((u >> 16) & 1u);          // round-to-nearest-even
    return (short)(u >> 16);
}
__device__ __forceinline__ float bf2f(short s) {
    unsigned u = ((unsigned)(unsigned short)s) << 16;
    return __builtin_bit_cast(float, u);
}

// ---------------------------------------------------------------------------
// prep1: kcT[n][t] = bf16(relu(b[n] + sum_dd C[t][dd]*W[dd][n])), n in [0,768)
// grid 48 (16 n each), block 256 = 64 t x 4 nl
// ---------------------------------------------------------------------------
__global__ __launch_bounds__(256) void kc_prep(const float* __restrict__ C,
                                               const float* __restrict__ W,
                                               const float* __restrict__ bias,
                                               short* __restrict__ kcT) {
    __shared__ float Ws[256 * 16];
    const int tid = threadIdx.x;
    const int n0  = blockIdx.x * 16;

    for (int idx = tid; idx < 256 * 16; idx += 256) {
        const int dd = idx >> 4, nl = idx & 15;
        Ws[idx] = W[dd * (KW * D_) + n0 + nl];
    }
    __syncthreads();

    const int t  = tid >> 2;
    const int nl = tid & 3;
    float acc[4];
    #pragma unroll
    for (int i = 0; i < 4; ++i) acc[i] = bias[n0 + nl + 4 * i];

    const float* Crow = C + t * D_;
    for (int dd = 0; dd < D_; ++dd) {
        const float cv = Crow[dd];
        #pragma unroll
        for (int i = 0; i < 4; ++i)
            acc[i] = fmaf(cv, Ws[dd * 16 + nl + 4 * i], acc[i]);
    }
    #pragma unroll
    for (int i = 0; i < 4; ++i)
        kcT[(n0 + nl + 4 * i) * T_ + t] = f2bf(fmaxf(acc[i], 0.f));
}

// ---------------------------------------------------------------------------
// prep2: M_j[dd][n'] = sum_t C[t][dd] * kc[t][j*256+n']  (j folded into n)
// Output packed in the main kernel's B-fragment order:
//   (k=dd, n) -> MPk[((((n>>4)*8 + (dd>>5))*4 + ((dd>>3)&3))*16 + (n&15))*8 + (dd&7)]
// grid 48 (one 16-col n-tile each), 4 waves: wave w does dd-tiles w*4..w*4+3.
// A-frag: A[row=dd0+c][k=t] = C[t][dd0+c]; B-frag: B[col=n0+c][k=t] = kcT[n][t].
// ---------------------------------------------------------------------------
__global__ __launch_bounds__(256) void m_prep(const float* __restrict__ C,
                                              const short* __restrict__ kcT,
                                              short* __restrict__ MPk) {
    const int tid  = threadIdx.x;
    const int w    = tid >> 6;
    const int lane = tid & 63;
    const int c    = lane & 15;
    const int g    = lane >> 4;
    const int nt   = blockIdx.x;          // 0..47
    const int n0   = nt * 16;

    const s16x8 B0 = *(const s16x8*)&kcT[(n0 + c) * T_ + 0 * 32 + g * 8];
    const s16x8 B1 = *(const s16x8*)&kcT[(n0 + c) * T_ + 1 * 32 + g * 8];

    #pragma unroll
    for (int q = 0; q < 4; ++q) {
        const int dd0 = (w * 4 + q) * 16;
        s16x8 a0, a1;
        #pragma unroll
        for (int e = 0; e < 8; ++e) {
            a0[e] = f2bf(C[(0 * 32 + g * 8 + e) * D_ + dd0 + c]);
            a1[e] = f2bf(C[(1 * 32 + g * 8 + e) * D_ + dd0 + c]);
        }
        f32x4 acc = (f32x4){0.f, 0.f, 0.f, 0.f};
        acc = __builtin_amdgcn_mfma_f32_16x16x32_bf16(a0, B0, acc, 0, 0, 0);
        acc = __builtin_amdgcn_mfma_f32_16x16x32_bf16(a1, B1, acc, 0, 0, 0);
        #pragma unroll
        for (int r = 0; r < 4; ++r) {
            const int dd = dd0 + g * 4 + r;
            const int ks2 = dd >> 5, g2 = (dd >> 3) & 3, e2 = dd & 7;
            MPk[(((nt * 8 + ks2) * 4 + g2) * 16 + c) * 8 + e2] = f2bf(acc[r]);
        }
    }
}

// ---------------------------------------------------------------------------
// main: out[l,d] = sum_j x[l-1+j,d] * (x[l,:] @ M_j)[d]
// Per block: 64 rows of one batch, 4 waves; wave w owns d in [w*64, w*64+64).
// xs bf16 [66][264] staged once (A-frags + fold); ONE barrier; B-frags from
// packed MPk (L2-resident, 1KB wave-contiguous loads, ks-halved for VGPR).
// LDS 34.8 KB -> 4 blocks/CU; __launch_bounds__(256,4) caps VGPR at 128.
// ---------------------------------------------------------------------------
#define XST 264

__global__ __launch_bounds__(256, 4) void main_kernel(const float* __restrict__ x,
                                                      const short* __restrict__ MPk,
                                                      float* __restrict__ out) {
    __shared__ short xs[66 * XST];        // 34848 B

    const int tid  = threadIdx.x;
    const int w    = tid >> 6;
    const int lane = tid & 63;
    const int c    = lane & 15;
    const int g    = lane >> 4;
    const int l0   = blockIdx.x * 64;
    const int b    = blockIdx.y;

    // ---- stage x rows l0-1 .. l0+64 as bf16 (coalesced, once) ----
    const f32x4* x4 = (const f32x4*)(x + (size_t)b * L_ * D_);
    #pragma unroll
    for (int k = 0; k < 17; ++k) {
        const int idx = tid + k * 256;
        if (idx < 66 * 64) {
            const int row = idx >> 6;
            const int d4  = idx & 63;
            const int l   = l0 - 1 + row;
            f32x4 v = (l >= 0 && l < L_) ? x4[(size_t)l * 64 + d4]
                                         : (f32x4){0.f, 0.f, 0.f, 0.f};
            s16x4 s;
            s[0] = f2bf(v[0]); s[1] = f2bf(v[1]); s[2] = f2bf(v[2]); s[3] = f2bf(v[3]);
            *(s16x4*)&xs[row * XST + d4 * 4] = s;
        }
    }
    __syncthreads();

    const size_t outBase = ((size_t)b * L_ + l0) * D_;

    for (int dtl = 0; dtl < 4; ++dtl) {
        const int dcol = w * 64 + dtl * 16 + c;
        const int nt   = (w * 4 + dtl);       // n-tile within j; j adds 16

        f32x4 acc[4][3];
        #pragma unroll
        for (int m = 0; m < 4; ++m)
            #pragma unroll
            for (int j = 0; j < 3; ++j)
                acc[m][j] = (f32x4){0.f, 0.f, 0.f, 0.f};

        #pragma unroll
        for (int half = 0; half < 2; ++half) {
            // B-frags for 3 j x 4 ks (wave-contiguous 1KB reads from L2)
            s16x8 Bf[3][4];
            #pragma unroll
            for (int j = 0; j < 3; ++j)
                #pragma unroll
                for (int k4 = 0; k4 < 4; ++k4)
                    Bf[j][k4] = *(const s16x8*)
                        &MPk[((((j * 16 + nt) * 8 + half * 4 + k4) * 4 + g) * 16 + c) * 8];

            #pragma unroll
            for (int k4 = 0; k4 < 4; ++k4) {
                const int ks = half * 4 + k4;
                s16x8 a0 = *(const s16x8*)&xs[(1 +  0 + c) * XST + ks * 32 + g * 8];
                s16x8 a1 = *(const s16x8*)&xs[(1 + 16 + c) * XST + ks * 32 + g * 8];
                s16x8 a2 = *(const s16x8*)&xs[(1 + 32 + c) * XST + ks * 32 + g * 8];
                s16x8 a3 = *(const s16x8*)&xs[(1 + 48 + c) * XST + ks * 32 + g * 8];
                #pragma unroll
                for (int j = 0; j < 3; ++j) {
                    acc[0][j] = __builtin_amdgcn_mfma_f32_16x16x32_bf16(a0, Bf[j][k4], acc[0][j], 0, 0, 0);
                    acc[1][j] = __builtin_amdgcn_mfma_f32_16x16x32_bf16(a1, Bf[j][k4], acc[1][j], 0, 0, 0);
                    acc[2][j] = __builtin_amdgcn_mfma_f32_16x16x32_bf16(a2, Bf[j][k4], acc[2][j], 0, 0, 0);
                    acc[3][j] = __builtin_amdgcn_mfma_f32_16x16x32_bf16(a3, Bf[j][k4], acc[3][j], 0, 0, 0);
                }
            }
        }

        // ---- fold 3-tap window + store ----
        #pragma unroll
        for (int m = 0; m < 4; ++m) {
            float xv[6];
            #pragma unroll
            for (int i = 0; i < 6; ++i)
                xv[i] = bf2f(xs[(m * 16 + g * 4 + i) * XST + dcol]);
            #pragma unroll
            for (int r = 0; r < 4; ++r) {
                const float o = acc[m][0][r] * xv[r]
                              + acc[m][1][r] * xv[r + 1]
                              + acc[m][2][r] * xv[r + 2];
                out[outBase + (size_t)(m * 16 + g * 4 + r) * D_ + dcol] = o;
            }
        }
    }
}

// ---------------------------------------------------------------------------
extern "C" void kernel_launch(void* const* d_in, const int* in_sizes, int n_in,
                              void* d_out, int out_size, void* d_ws, size_t ws_size,
                              hipStream_t stream) {
    const float* x    = (const float*)d_in[0];
    const float* C    = (const float*)d_in[1];
    const float* Wden = (const float*)d_in[2];
    const float* bden = (const float*)d_in[3];
    float* out = (float*)d_out;

    short* kcT = (short*)d_ws;                       // 768*64  = 49152 shorts
    short* MPk = (short*)d_ws + KW * D_ * T_;        // 3*256*256 = 196608 shorts

    kc_prep<<<dim3(48), dim3(256), 0, stream>>>(C, Wden, bden, kcT);
    m_prep<<<dim3(48), dim3(256), 0, stream>>>(C, kcT, MPk);

    dim3 grid(L_ / 64, B_);
    main_kernel<<<grid, dim3(256), 0, stream>>>(x, MPk, out);
}

// Round 13
// 68.275 us; speedup vs baseline: 2.0788x; 2.0788x over previous
//
#include <hip/hip_runtime.h>

// Problem constants
#define B_  32
#define L_  2048
#define D_  256
#define T_  64
#define KW  3

typedef float f32x4 __attribute__((ext_vector_type(4)));
typedef short s16x8 __attribute__((ext_vector_type(8)));
typedef short s16x4 __attribute__((ext_vector_type(4)));

__device__ __forceinline__ short f2bf(float f) {
    unsigned u = __builtin_bit_cast(unsigned, f);
    u += 0x7FFFu + ((u >> 16) & 1u);          // round-to-nearest-even
    return (short)(u >> 16);
}
__device__ __forceinline__ float bf2f(short s) {
    unsigned u = ((unsigned)(unsigned short)s) << 16;
    return __builtin_bit_cast(float, u);
}

// ---------------------------------------------------------------------------
// prep1: kcT[n][t] = bf16(relu(b[n] + sum_dd C[t][dd]*W[dd][n])), n in [0,768)
// ---------------------------------------------------------------------------
__global__ __launch_bounds__(256) void kc_prep(const float* __restrict__ C,
                                               const float* __restrict__ W,
                                               const float* __restrict__ bias,
                                               short* __restrict__ kcT) {
    __shared__ float Ws[256 * 16];
    const int tid = threadIdx.x;
    const int n0  = blockIdx.x * 16;

    for (int idx = tid; idx < 256 * 16; idx += 256) {
        const int dd = idx >> 4, nl = idx & 15;
        Ws[idx] = W[dd * (KW * D_) + n0 + nl];
    }
    __syncthreads();

    const int t  = tid >> 2;
    const int nl = tid & 3;
    float acc[4];
    #pragma unroll
    for (int i = 0; i < 4; ++i) acc[i] = bias[n0 + nl + 4 * i];

    const float* Crow = C + t * D_;
    for (int dd = 0; dd < D_; ++dd) {
        const float cv = Crow[dd];
        #pragma unroll
        for (int i = 0; i < 4; ++i)
            acc[i] = fmaf(cv, Ws[dd * 16 + nl + 4 * i], acc[i]);
    }
    #pragma unroll
    for (int i = 0; i < 4; ++i)
        kcT[(n0 + nl + 4 * i) * T_ + t] = f2bf(fmaxf(acc[i], 0.f));
}

// ---------------------------------------------------------------------------
// prep2: M_j[dd][n'] = sum_t C[t][dd] * kc[t][j*256+n'] packed in main's
// B-fragment order: (k=dd,n) ->
//   MPk[((((n>>4)*8 + (dd>>5))*4 + ((dd>>3)&3))*16 + (n&15))*8 + (dd&7)]
// ---------------------------------------------------------------------------
__global__ __launch_bounds__(256) void m_prep(const float* __restrict__ C,
                                              const short* __restrict__ kcT,
                                              short* __restrict__ MPk) {
    const int tid  = threadIdx.x;
    const int w    = tid >> 6;
    const int lane = tid & 63;
    const int c    = lane & 15;
    const int g    = lane >> 4;
    const int nt   = blockIdx.x;          // 0..47
    const int n0   = nt * 16;

    const s16x8 B0 = *(const s16x8*)&kcT[(n0 + c) * T_ + 0 * 32 + g * 8];
    const s16x8 B1 = *(const s16x8*)&kcT[(n0 + c) * T_ + 1 * 32 + g * 8];

    #pragma unroll
    for (int q = 0; q < 4; ++q) {
        const int dd0 = (w * 4 + q) * 16;
        s16x8 a0, a1;
        #pragma unroll
        for (int e = 0; e < 8; ++e) {
            a0[e] = f2bf(C[(0 * 32 + g * 8 + e) * D_ + dd0 + c]);
            a1[e] = f2bf(C[(1 * 32 + g * 8 + e) * D_ + dd0 + c]);
        }
        f32x4 acc = (f32x4){0.f, 0.f, 0.f, 0.f};
        acc = __builtin_amdgcn_mfma_f32_16x16x32_bf16(a0, B0, acc, 0, 0, 0);
        acc = __builtin_amdgcn_mfma_f32_16x16x32_bf16(a1, B1, acc, 0, 0, 0);
        #pragma unroll
        for (int r = 0; r < 4; ++r) {
            const int dd = dd0 + g * 4 + r;
            const int ks2 = dd >> 5, g2 = (dd >> 3) & 3, e2 = dd & 7;
            MPk[(((nt * 8 + ks2) * 4 + g2) * 16 + c) * 8 + e2] = f2bf(acc[r]);
        }
    }
}

// ---------------------------------------------------------------------------
// main: out[l,d] = sum_j x[l-1+j,d] * (x[l,:] @ M_j)[d]
// Per block: 64 rows of one batch, 4 waves; wave w owns d in [w*64, w*64+64).
// REGISTER-SANE schedule: B-frags loaded per ks-step (3 live, not 24);
// acc[4][3] (48 VGPR) + 2-deep unroll -> ~116 live VGPR, no spill.
// Each M element still read exactly once per wave (reused across 4 m-tiles).
// ---------------------------------------------------------------------------
#define XST 264

__global__ __launch_bounds__(256, 4) void main_kernel(const float* __restrict__ x,
                                                      const short* __restrict__ MPk,
                                                      float* __restrict__ out) {
    __shared__ short xs[66 * XST];        // 34848 B

    const int tid  = threadIdx.x;
    const int w    = tid >> 6;
    const int lane = tid & 63;
    const int c    = lane & 15;
    const int g    = lane >> 4;
    const int l0   = blockIdx.x * 64;
    const int b    = blockIdx.y;

    // ---- stage x rows l0-1 .. l0+64 as bf16 (coalesced, once) ----
    const f32x4* x4 = (const f32x4*)(x + (size_t)b * L_ * D_);
    #pragma unroll
    for (int k = 0; k < 17; ++k) {
        const int idx = tid + k * 256;
        if (idx < 66 * 64) {
            const int row = idx >> 6;
            const int d4  = idx & 63;
            const int l   = l0 - 1 + row;
            f32x4 v = (l >= 0 && l < L_) ? x4[(size_t)l * 64 + d4]
                                         : (f32x4){0.f, 0.f, 0.f, 0.f};
            s16x4 s;
            s[0] = f2bf(v[0]); s[1] = f2bf(v[1]); s[2] = f2bf(v[2]); s[3] = f2bf(v[3]);
            *(s16x4*)&xs[row * XST + d4 * 4] = s;
        }
    }
    __syncthreads();

    const size_t outBase = ((size_t)b * L_ + l0) * D_;

    for (int dtl = 0; dtl < 4; ++dtl) {
        const int dcol = w * 64 + dtl * 16 + c;
        const int nt   = w * 4 + dtl;        // n-tile within j; j adds 16

        f32x4 acc[4][3];
        #pragma unroll
        for (int m = 0; m < 4; ++m)
            #pragma unroll
            for (int j = 0; j < 3; ++j)
                acc[m][j] = (f32x4){0.f, 0.f, 0.f, 0.f};

        #pragma unroll 2
        for (int ks = 0; ks < 8; ++ks) {
            // 3 B-frags for this ks (12 VGPR live, reused across 4 m-tiles)
            const s16x8 Bf0 = *(const s16x8*)
                &MPk[((((0 * 16 + nt) * 8 + ks) * 4 + g) * 16 + c) * 8];
            const s16x8 Bf1 = *(const s16x8*)
                &MPk[((((1 * 16 + nt) * 8 + ks) * 4 + g) * 16 + c) * 8];
            const s16x8 Bf2 = *(const s16x8*)
                &MPk[((((2 * 16 + nt) * 8 + ks) * 4 + g) * 16 + c) * 8];

            const s16x8 a0 = *(const s16x8*)&xs[(1 +  0 + c) * XST + ks * 32 + g * 8];
            const s16x8 a1 = *(const s16x8*)&xs[(1 + 16 + c) * XST + ks * 32 + g * 8];
            const s16x8 a2 = *(const s16x8*)&xs[(1 + 32 + c) * XST + ks * 32 + g * 8];
            const s16x8 a3 = *(const s16x8*)&xs[(1 + 48 + c) * XST + ks * 32 + g * 8];

            acc[0][0] = __builtin_amdgcn_mfma_f32_16x16x32_bf16(a0, Bf0, acc[0][0], 0, 0, 0);
            acc[1][0] = __builtin_amdgcn_mfma_f32_16x16x32_bf16(a1, Bf0, acc[1][0], 0, 0, 0);
            acc[2][0] = __builtin_amdgcn_mfma_f32_16x16x32_bf16(a2, Bf0, acc[2][0], 0, 0, 0);
            acc[3][0] = __builtin_amdgcn_mfma_f32_16x16x32_bf16(a3, Bf0, acc[3][0], 0, 0, 0);
            acc[0][1] = __builtin_amdgcn_mfma_f32_16x16x32_bf16(a0, Bf1, acc[0][1], 0, 0, 0);
            acc[1][1] = __builtin_amdgcn_mfma_f32_16x16x32_bf16(a1, Bf1, acc[1][1], 0, 0, 0);
            acc[2][1] = __builtin_amdgcn_mfma_f32_16x16x32_bf16(a2, Bf1, acc[2][1], 0, 0, 0);
            acc[3][1] = __builtin_amdgcn_mfma_f32_16x16x32_bf16(a3, Bf1, acc[3][1], 0, 0, 0);
            acc[0][2] = __builtin_amdgcn_mfma_f32_16x16x32_bf16(a0, Bf2, acc[0][2], 0, 0, 0);
            acc[1][2] = __builtin_amdgcn_mfma_f32_16x16x32_bf16(a1, Bf2, acc[1][2], 0, 0, 0);
            acc[2][2] = __builtin_amdgcn_mfma_f32_16x16x32_bf16(a2, Bf2, acc[2][2], 0, 0, 0);
            acc[3][2] = __builtin_amdgcn_mfma_f32_16x16x32_bf16(a3, Bf2, acc[3][2], 0, 0, 0);
        }

        // ---- fold 3-tap window + store ----
        #pragma unroll
        for (int m = 0; m < 4; ++m) {
            float xv[6];
            #pragma unroll
            for (int i = 0; i < 6; ++i)
                xv[i] = bf2f(xs[(m * 16 + g * 4 + i) * XST + dcol]);
            #pragma unroll
            for (int r = 0; r < 4; ++r) {
                const float o = acc[m][0][r] * xv[r]
                              + acc[m][1][r] * xv[r + 1]
                              + acc[m][2][r] * xv[r + 2];
                out[outBase + (size_t)(m * 16 + g * 4 + r) * D_ + dcol] = o;
            }
        }
    }
}

// ---------------------------------------------------------------------------
extern "C" void kernel_launch(void* const* d_in, const int* in_sizes, int n_in,
                              void* d_out, int out_size, void* d_ws, size_t ws_size,
                              hipStream_t stream) {
    const float* x    = (const float*)d_in[0];
    const float* C    = (const float*)d_in[1];
    const float* Wden = (const float*)d_in[2];
    const float* bden = (const float*)d_in[3];
    float* out = (float*)d_out;

    short* kcT = (short*)d_ws;                       // 768*64  = 49152 shorts
    short* MPk = (short*)d_ws + KW * D_ * T_;        // 3*256*256 = 196608 shorts

    kc_prep<<<dim3(48), dim3(256), 0, stream>>>(C, Wden, bden, kcT);
    m_prep<<<dim3(48), dim3(256), 0, stream>>>(C, kcT, MPk);

    dim3 grid(L_ / 64, B_);
    main_kernel<<<grid, dim3(256), 0, stream>>>(x, MPk, out);
}

// Round 14
// 49.901 us; speedup vs baseline: 2.8443x; 1.3682x over previous
//
#include <hip/hip_runtime.h>

// Problem constants
#define B_  32
#define L_  2048
#define D_  256
#define T_  64
#define KW  3
#define ROWS  16          // rows per block
#define XROWS 18          // rows + 2 halo

typedef float f32x4 __attribute__((ext_vector_type(4)));
typedef short s16x8 __attribute__((ext_vector_type(8)));
typedef short s16x4 __attribute__((ext_vector_type(4)));

__device__ __forceinline__ short f2bf(float f) {
    unsigned u = __builtin_bit_cast(unsigned, f);
    u += 0x7FFFu + ((u >> 16) & 1u);          // round-to-nearest-even
    return (short)(u >> 16);
}
__device__ __forceinline__ float bf2f(short s) {
    unsigned u = ((unsigned)(unsigned short)s) << 16;
    return __builtin_bit_cast(float, u);
}

// Pinned global load: compiler cannot sink this past its textual position
// (asm volatile + memory clobber). Result regs fill when vmcnt retires.
__device__ __forceinline__ s16x8 aload(const short* p) {
    s16x8 r;
    asm volatile("global_load_dwordx4 %0, %1, off"
                 : "=&v"(r) : "v"(p) : "memory");
    return r;
}

// ---------------------------------------------------------------------------
// fused prep (one launch):
//  bx <  16 : CbfPk = bf16(C) packed in phase-1 B-fragment order
//  bx >= 16 : kcPk = packed relu(C@W+b) in phase-2 B-fragment order
// ---------------------------------------------------------------------------
__global__ __launch_bounds__(256) void prep_kernel(const float* __restrict__ C,
                                                   const float* __restrict__ W,
                                                   const float* __restrict__ bias,
                                                   short* __restrict__ CbfPk,
                                                   short* __restrict__ kcPk) {
    __shared__ float Ws[256 * 16];
    const int tid = threadIdx.x;

    if (blockIdx.x < 16) {
        const int i0 = (blockIdx.x * 256 + tid) * 4;
        const int t = i0 >> 8, d = i0 & 255;
        const f32x4 v = *(const f32x4*)(C + i0);
        s16x4 s;
        s[0] = f2bf(v[0]); s[1] = f2bf(v[1]); s[2] = f2bf(v[2]); s[3] = f2bf(v[3]);
        const int tt = t >> 4, c = t & 15, ks = d >> 5, gg = (d >> 3) & 3, e = d & 7;
        *(s16x4*)&CbfPk[(((tt * 8 + ks) * 4 + gg) * 16 + c) * 8 + e] = s;
        return;
    }

    const int nb = blockIdx.x - 16;
    const int n0 = nb * 16;

    for (int idx = tid; idx < 256 * 16; idx += 256) {
        const int dd = idx >> 4, nl = idx & 15;
        Ws[idx] = W[dd * (KW * D_) + n0 + nl];
    }
    __syncthreads();

    const int t  = tid >> 2;
    const int nl = tid & 3;
    float acc[4];
    #pragma unroll
    for (int i = 0; i < 4; ++i) acc[i] = bias[n0 + nl + 4 * i];

    const float* Crow = C + t * D_;
    for (int dd = 0; dd < D_; ++dd) {
        const float cv = Crow[dd];
        #pragma unroll
        for (int i = 0; i < 4; ++i)
            acc[i] = fmaf(cv, Ws[dd * 16 + nl + 4 * i], acc[i]);
    }
    const int ks = t >> 5, gg = (t >> 3) & 3, e = t & 7;
    #pragma unroll
    for (int i = 0; i < 4; ++i) {
        const int cc = nl + 4 * i;
        kcPk[(((nb * 2 + ks) * 4 + gg) * 16 + cc) * 8 + e] = f2bf(fmaxf(acc[i], 0.f));
    }
}

// ---------------------------------------------------------------------------
// main: R6 structure (16-row tiles, 4 waves, 12 KB LDS) + asm-pinned
// prefetch of phase-2 B-fragments:
//   - F(dtl=0..2): 18 global_load_dwordx4 issued BEFORE staging; the
//     __syncthreads vmcnt(0) drain guarantees completion, staging+ph1
//     (~1500 cy) is free latency cover.
//   - F(dtl=3): issued after dtl0's compute; register-tied s_waitcnt
//     vmcnt(0) + sched_barrier(0) before its MFMAs.
// ---------------------------------------------------------------------------
#define XST 264
#define ATS 72

#define BADDR(J, DTL, KS) \
    (&kcPk[(((((J) * 16 + w * 4 + (DTL)) * 2 + (KS)) * 4 + g) * 16 + c) * 8])

__global__ __launch_bounds__(256, 4) void main_kernel(const float* __restrict__ x,
                                                      const short* __restrict__ CbfPk,
                                                      const short* __restrict__ kcPk,
                                                      float* __restrict__ out) {
    __shared__ short xs[XROWS * XST];      // 9504 B
    __shared__ short atts[ROWS * ATS];     // 2304 B

    const int tid  = threadIdx.x;
    const int w    = tid >> 6;        // wave 0..3
    const int lane = tid & 63;
    const int c    = lane & 15;
    const int g    = lane >> 4;
    const int l0   = blockIdx.x * ROWS;
    const int b    = blockIdx.y;

    // ---- pinned-issue phase-2 B-frags for dtl 0..2 (18 loads in flight) ----
    s16x8 f0_0 = aload(BADDR(0, 0, 0));
    s16x8 f0_1 = aload(BADDR(0, 0, 1));
    s16x8 f0_2 = aload(BADDR(1, 0, 0));
    s16x8 f0_3 = aload(BADDR(1, 0, 1));
    s16x8 f0_4 = aload(BADDR(2, 0, 0));
    s16x8 f0_5 = aload(BADDR(2, 0, 1));
    s16x8 f1_0 = aload(BADDR(0, 1, 0));
    s16x8 f1_1 = aload(BADDR(0, 1, 1));
    s16x8 f1_2 = aload(BADDR(1, 1, 0));
    s16x8 f1_3 = aload(BADDR(1, 1, 1));
    s16x8 f1_4 = aload(BADDR(2, 1, 0));
    s16x8 f1_5 = aload(BADDR(2, 1, 1));
    s16x8 f2_0 = aload(BADDR(0, 2, 0));
    s16x8 f2_1 = aload(BADDR(0, 2, 1));
    s16x8 f2_2 = aload(BADDR(1, 2, 0));
    s16x8 f2_3 = aload(BADDR(1, 2, 1));
    s16x8 f2_4 = aload(BADDR(2, 2, 0));
    s16x8 f2_5 = aload(BADDR(2, 2, 1));

    // ---- stage x rows l0-1 .. l0+16 as bf16 (coalesced, once) ----
    const f32x4* x4 = (const f32x4*)(x + (size_t)b * L_ * D_);
    for (int idx = tid; idx < XROWS * 64; idx += 256) {
        const int row = idx >> 6;
        const int d4  = idx & 63;
        const int l   = l0 - 1 + row;
        f32x4 v = {0.f, 0.f, 0.f, 0.f};
        if (l >= 0 && l < L_) v = x4[(size_t)l * 64 + d4];
        s16x4 s;
        s[0] = f2bf(v[0]); s[1] = f2bf(v[1]); s[2] = f2bf(v[2]); s[3] = f2bf(v[3]);
        *(s16x4*)&xs[row * XST + d4 * 4] = s;
    }
    __syncthreads();   // vmcnt(0) drain: f0_*/f1_*/f2_* complete here

    // ---- phase 1: wave w computes all 16 rows x t-tile w ----
    {
        f32x4 acc = (f32x4){0.f, 0.f, 0.f, 0.f};
        const short* xr = &xs[(1 + c) * XST];
        #pragma unroll
        for (int ks = 0; ks < 8; ++ks) {
            const s16x8 cb = *(const s16x8*)&CbfPk[(((w * 8 + ks) * 4 + g) * 16 + c) * 8];
            const s16x8 a  = *(const s16x8*)&xr[ks * 32 + g * 8];
            acc = __builtin_amdgcn_mfma_f32_16x16x32_bf16(a, cb, acc, 0, 0, 0);
        }
        #pragma unroll
        for (int r = 0; r < 4; ++r)
            atts[(g * 4 + r) * ATS + w * 16 + c] = f2bf(acc[r]);
    }
    __syncthreads();

    // ---- phase 2 ----
    const s16x8 afr0 = *(const s16x8*)&atts[c * ATS + 0 * 32 + g * 8];
    const s16x8 afr1 = *(const s16x8*)&atts[c * ATS + 1 * 32 + g * 8];

    const size_t outBase = ((size_t)b * L_ + l0) * D_;

#define PH2_STEP(B0, B1, B2, B3, B4, B5, DTL)                                   \
    {                                                                           \
        const int dcol = w * 64 + (DTL) * 16 + c;                               \
        f32x4 a0 = (f32x4){0.f,0.f,0.f,0.f};                                    \
        f32x4 a1 = (f32x4){0.f,0.f,0.f,0.f};                                    \
        f32x4 a2 = (f32x4){0.f,0.f,0.f,0.f};                                    \
        a0 = __builtin_amdgcn_mfma_f32_16x16x32_bf16(afr0, B0, a0, 0, 0, 0);    \
        a0 = __builtin_amdgcn_mfma_f32_16x16x32_bf16(afr1, B1, a0, 0, 0, 0);    \
        a1 = __builtin_amdgcn_mfma_f32_16x16x32_bf16(afr0, B2, a1, 0, 0, 0);    \
        a1 = __builtin_amdgcn_mfma_f32_16x16x32_bf16(afr1, B3, a1, 0, 0, 0);    \
        a2 = __builtin_amdgcn_mfma_f32_16x16x32_bf16(afr0, B4, a2, 0, 0, 0);    \
        a2 = __builtin_amdgcn_mfma_f32_16x16x32_bf16(afr1, B5, a2, 0, 0, 0);    \
        float xv[6];                                                            \
        _Pragma("unroll")                                                       \
        for (int i = 0; i < 6; ++i)                                             \
            xv[i] = bf2f(xs[(g * 4 + i) * XST + dcol]);                         \
        _Pragma("unroll")                                                       \
        for (int r = 0; r < 4; ++r) {                                           \
            const float o = a0[r] * xv[r] + a1[r] * xv[r + 1] + a2[r] * xv[r + 2]; \
            out[outBase + (size_t)(g * 4 + r) * D_ + dcol] = o;                 \
        }                                                                       \
    }

    // dtl 0 (frags ready since barrier)
    PH2_STEP(f0_0, f0_1, f0_2, f0_3, f0_4, f0_5, 0);

    // pinned-issue dtl3 frags; MFMA of dtl1/dtl2 is their latency cover
    s16x8 f3_0 = aload(BADDR(0, 3, 0));
    s16x8 f3_1 = aload(BADDR(0, 3, 1));
    s16x8 f3_2 = aload(BADDR(1, 3, 0));
    s16x8 f3_3 = aload(BADDR(1, 3, 1));
    s16x8 f3_4 = aload(BADDR(2, 3, 0));
    s16x8 f3_5 = aload(BADDR(2, 3, 1));

    PH2_STEP(f1_0, f1_1, f1_2, f1_3, f1_4, f1_5, 1);
    PH2_STEP(f2_0, f2_1, f2_2, f2_3, f2_4, f2_5, 2);

    // safe full drain before consuming f3_* (register-tied; rule #18 fence)
    asm volatile("s_waitcnt vmcnt(0)"
                 : "+v"(f3_0), "+v"(f3_1), "+v"(f3_2),
                   "+v"(f3_3), "+v"(f3_4), "+v"(f3_5)
                 :: "memory");
    __builtin_amdgcn_sched_barrier(0);

    PH2_STEP(f3_0, f3_1, f3_2, f3_3, f3_4, f3_5, 3);

#undef PH2_STEP
}

// ---------------------------------------------------------------------------
extern "C" void kernel_launch(void* const* d_in, const int* in_sizes, int n_in,
                              void* d_out, int out_size, void* d_ws, size_t ws_size,
                              hipStream_t stream) {
    const float* x    = (const float*)d_in[0];
    const float* C    = (const float*)d_in[1];
    const float* Wden = (const float*)d_in[2];
    const float* bden = (const float*)d_in[3];
    float* out = (float*)d_out;

    short* kcPk  = (short*)d_ws;                   // [768][64] bf16 = 98304 B
    short* CbfPk = (short*)d_ws + KW * D_ * T_;    // [64][256] bf16 = 32768 B

    prep_kernel<<<dim3(64), dim3(256), 0, stream>>>(C, Wden, bden, CbfPk, kcPk);

    dim3 grid(L_ / ROWS, B_);
    main_kernel<<<grid, dim3(256), 0, stream>>>(x, CbfPk, kcPk, out);
}